// Round 5
// baseline (67.790 us; speedup 1.0000x reference)
//
#include <hip/hip_runtime.h>
#include <hip/hip_bf16.h>

#define BB 4096
#define SS 128
#define DIMQ 512
#define DIMZ 64
#define HIDV 512

typedef __attribute__((ext_vector_type(8))) short sh8;
typedef __attribute__((ext_vector_type(4))) float f32x4;

__device__ inline unsigned short f2bf(float f) {
    unsigned u = __float_as_uint(f);
    return (unsigned short)((u + 0x7fffu + ((u >> 16) & 1u)) >> 16);
}

// Prep: W1qT[n][k]=bf16(W1[k][n]) k<512; cvec = b1 + z@W1[512:576]; zero Vnet.
__global__ __launch_bounds__(256) void k_prep(const float* __restrict__ W1,
        const float* __restrict__ z, const float* __restrict__ b1,
        unsigned short* __restrict__ W1qT, float* __restrict__ cvec,
        float* __restrict__ Vnet) {
    __shared__ float tile[32][33];
    int bx = blockIdx.x & 15, by = blockIdx.x >> 4;
    int k0 = by * 32, n0 = bx * 32;
    int tx = threadIdx.x & 31, tg = threadIdx.x >> 5;
    #pragma unroll
    for (int rr = 0; rr < 4; rr++) {
        int ty = tg * 4 + rr;
        tile[ty][tx] = W1[(size_t)(k0 + ty) * HIDV + n0 + tx];
    }
    __syncthreads();
    #pragma unroll
    for (int rr = 0; rr < 4; rr++) {
        int ty = tg * 4 + rr;
        W1qT[(size_t)(n0 + ty) * DIMQ + k0 + tx] = f2bf(tile[tx][ty]);
    }
    if (blockIdx.x < 2) {
        int h = blockIdx.x * 256 + threadIdx.x;
        float acc = b1[h];
        #pragma unroll 8
        for (int k = 0; k < DIMZ; k++) acc += z[k] * W1[(size_t)(DIMQ + k) * HIDV + h];
        cvec[h] = acc;
    }
    if (blockIdx.x < 12) {
        int i = blockIdx.x * 1024 + threadIdx.x * 4;
        float4 zv = {0.f, 0.f, 0.f, 0.f};
        *(float4*)(Vnet + i) = zv;
    }
}

// K1: blocks 0..383 = GEMM for e0/e1/e2 (A from f32 inputs, reg-staged -> bf16,
//     tanh partials atomicAdd into Vnet). blocks 384..2431 = scan (2 batches each,
//     sums -> bases '=' into out, qtraj, no staging buffers).
__global__ __launch_bounds__(256) void k_main(
        const float* __restrict__ u, const float* __restrict__ q0off,
        const float* __restrict__ p0off, const float* __restrict__ q0on,
        const float* __restrict__ p0on, const float* __restrict__ b2,
        const unsigned short* __restrict__ W1qT, const float* __restrict__ cvec,
        const float* __restrict__ W2, float* __restrict__ Vnet,
        float* __restrict__ out, float* __restrict__ qtraj,
        float R00, float R01, float R10, float R11) {
    __shared__ __attribute__((aligned(16))) char lds[65536];
    const int t = threadIdx.x;

    if (blockIdx.x < 384) {
        // ---------------- GEMM e0/e1/e2 ----------------
        const int gi = blockIdx.x;
        const int e = gi >> 7;               // 0,1,2
        const int rtc = gi & 127;
        const int rowBase = (rtc >> 2) * 128;   // batch index base
        const int colBase = (rtc & 3) * 128;
        const int lane = t & 63;
        const int w = t >> 6;
        const int wr = w >> 1, wc = w & 1;
        const float* srcA = (e == 2) ? q0on : q0off;

        // LDS: A dbuf @0,16384 ; B dbuf @32768,49152
        f32x4 acc[4][4] = {};
        float4 Aq[4][2], Ap[4][2];

        auto LOAD_A = [&](int kt) {
            #pragma unroll
            for (int i = 0; i < 4; i++) {
                int ch = i * 256 + t, r = ch >> 3, cb = ch & 7;
                const float* ba = srcA + (size_t)(rowBase + r) * 512 + kt * 64 + cb * 8;
                Aq[i][0] = *(const float4*)ba;
                Aq[i][1] = *(const float4*)(ba + 4);
                if (e == 1) {
                    const float* bp = p0off + (size_t)(rowBase + r) * 512 + kt * 64 + cb * 8;
                    Ap[i][0] = *(const float4*)bp;
                    Ap[i][1] = *(const float4*)(bp + 4);
                }
            }
        };
        auto WRITE_A = [&](int buf) {
            char* dA = lds + buf * 16384;
            #pragma unroll
            for (int i = 0; i < 4; i++) {
                int ch = i * 256 + t, r = ch >> 3, cb = ch & 7;
                sh8 v;
                #pragma unroll
                for (int c2 = 0; c2 < 8; c2++) {
                    float qv = (c2 < 4) ? Aq[i][0][c2] : Aq[i][1][c2 - 4];
                    if (e == 1) {
                        float pv = (c2 < 4) ? Ap[i][0][c2] : Ap[i][1][c2 - 4];
                        qv = R00 * qv + R01 * pv;
                    }
                    v[c2] = (short)f2bf(qv);
                }
                *(sh8*)(dA + r * 128 + ((cb << 4) ^ ((r & 7) << 4))) = v;
            }
        };
        auto STAGE_B = [&](int kt, int buf) {
            char* dB = lds + 32768 + buf * 16384;
            #pragma unroll
            for (int i = 0; i < 4; i++) {
                unsigned ch = i * 256 + t;
                unsigned r = ch >> 3;
                unsigned scb = (ch & 7) ^ (r & 7);
                const unsigned short* src = W1qT + (size_t)(colBase + r) * 512 + (unsigned)kt * 64 + scb * 8;
                __builtin_amdgcn_global_load_lds(
                    (const __attribute__((address_space(1))) unsigned int*)(const void*)src,
                    (__attribute__((address_space(3))) unsigned int*)(void*)(dB + ch * 16), 16, 0, 0);
            }
        };

        LOAD_A(0);
        STAGE_B(0, 0);
        WRITE_A(0);
        asm volatile("s_waitcnt vmcnt(0) lgkmcnt(0)" ::: "memory");
        __builtin_amdgcn_s_barrier();

        for (int kt = 0; kt < 8; kt++) {
            int cur = kt & 1;
            if (kt < 7) { LOAD_A(kt + 1); STAGE_B(kt + 1, cur ^ 1); }
            char* ldsA = lds + cur * 16384;
            char* ldsB = lds + 32768 + cur * 16384;
            #pragma unroll
            for (int ks = 0; ks < 2; ks++) {
                sh8 af[4], bf_[4];
                int kb = ks * 64 + ((lane >> 4) << 4);
                #pragma unroll
                for (int mi = 0; mi < 4; mi++) {
                    int m = wr * 64 + mi * 16 + (lane & 15);
                    af[mi] = *(const sh8*)(ldsA + m * 128 + (kb ^ ((m & 7) << 4)));
                }
                #pragma unroll
                for (int ni = 0; ni < 4; ni++) {
                    int n = wc * 64 + ni * 16 + (lane & 15);
                    bf_[ni] = *(const sh8*)(ldsB + n * 128 + (kb ^ ((n & 7) << 4)));
                }
                #pragma unroll
                for (int mi = 0; mi < 4; mi++)
                    #pragma unroll
                    for (int ni = 0; ni < 4; ni++)
                        acc[mi][ni] = __builtin_amdgcn_mfma_f32_16x16x32_bf16(af[mi], bf_[ni], acc[mi][ni], 0, 0, 0);
            }
            if (kt < 7) WRITE_A(cur ^ 1);
            asm volatile("s_waitcnt vmcnt(0) lgkmcnt(0)" ::: "memory");
            __builtin_amdgcn_s_barrier();
        }

        float w2v[4], cv[4];
        #pragma unroll
        for (int ni = 0; ni < 4; ni++) {
            int n = colBase + wc * 64 + ni * 16 + (lane & 15);
            w2v[ni] = W2[n];
            cv[ni] = cvec[n];
        }
        #pragma unroll
        for (int mi = 0; mi < 4; mi++) {
            #pragma unroll
            for (int r = 0; r < 4; r++) {
                float partial = 0.f;
                #pragma unroll
                for (int ni = 0; ni < 4; ni++)
                    partial += tanhf(acc[mi][ni][r] + cv[ni]) * w2v[ni];
                partial += __shfl_xor(partial, 1, 64);
                partial += __shfl_xor(partial, 2, 64);
                partial += __shfl_xor(partial, 4, 64);
                partial += __shfl_xor(partial, 8, 64);
                if ((lane & 15) == 0) {
                    int row = rowBase + wr * 64 + mi * 16 + ((lane >> 4) << 2) + r;
                    atomicAdd(Vnet + e * BB + row, partial);
                }
            }
        }
        return;
    }

    // ---------------- scan path ----------------
    int half = t >> 7;
    int tc = t & 127;
    int b = (blockIdx.x - 384) * 2 + half;
    int j = tc * 4;
    size_t idx = (size_t)b * DIMQ + j;
    float q[4], p[4], qo[4], po[4];
    *(float4*)q  = *(const float4*)(q0off + idx);
    *(float4*)p  = *(const float4*)(p0off + idx);
    *(float4*)qo = *(const float4*)(q0on + idx);
    *(float4*)po = *(const float4*)(p0on + idx);

    float sums[8] = {0, 0, 0, 0, 0, 0, 0, 0};
    float q2[4], p2[4];
    #pragma unroll
    for (int c = 0; c < 4; c++) {
        float qq = q[c], pp = p[c];
        sums[0] += qq * qq;
        sums[1] += pp * pp;
        float qf = R00 * qq + R01 * pp;
        float pf = R10 * qq + R11 * pp;
        sums[2] += qf * qf;
        sums[3] += pf * pf;
        q2[c] = qo[c]; p2[c] = po[c];
        sums[4] += q2[c] * q2[c];
        sums[5] += p2[c] * p2[c];
    }
    const float* ub = u + (size_t)b * SS * DIMQ + j;
    #pragma unroll
    for (int st = 0; st < 10; st++) {
        float uv[4];
        *(float4*)uv = *(const float4*)(ub + (size_t)st * DIMQ);
        #pragma unroll
        for (int c = 0; c < 4; c++) {
            p2[c] = (p2[c] - 0.1f * (0.1f * q2[c]) + 0.1f * (0.1f * uv[c])) * 0.99f;
            q2[c] = q2[c] + 0.1f * p2[c];
        }
    }
    #pragma unroll
    for (int c = 0; c < 4; c++) {
        sums[6] += q2[c] * q2[c];
        sums[7] += p2[c] * p2[c];
    }
    *(float4*)(qtraj + idx) = *(float4*)q2;

    float* red = (float*)lds;   // [2][2][8]
    int lane = t & 63, wv = (t >> 6) & 1;
    #pragma unroll
    for (int k = 0; k < 8; k++) {
        float v = sums[k];
        #pragma unroll
        for (int m = 1; m < 64; m <<= 1) v += __shfl_xor(v, m, 64);
        if (lane == 0) red[(half * 2 + wv) * 8 + k] = v;
    }
    __syncthreads();
    if (tc < 4) {
        int e = tc;
        float sq = red[(half * 2) * 8 + 2 * e] + red[(half * 2 + 1) * 8 + 2 * e];
        float sp = red[(half * 2) * 8 + 2 * e + 1] + red[(half * 2 + 1) * 8 + 2 * e + 1];
        float F = 0.5f * sp + 0.05f * sq + b2[0];
        size_t o = (size_t)b * 2 + (e & 1) + (size_t)(e >> 1) * 2 * BB;
        out[o] = F;
    }
}

// K2: blocks 0..127 = GEMM e3 (A from qtraj f32, atomicAdd onto out e3 base);
//     blocks 128..175 = finalize: out[e012] += Vnet.
__global__ __launch_bounds__(256) void k_tail(
        const float* __restrict__ qtraj, const unsigned short* __restrict__ W1qT,
        const float* __restrict__ cvec, const float* __restrict__ W2,
        const float* __restrict__ Vnet, float* __restrict__ out) {
    __shared__ __attribute__((aligned(16))) char lds[65536];
    const int t = threadIdx.x;

    if (blockIdx.x >= 128) {
        int i = (blockIdx.x - 128) * 256 + t;   // 0..12287
        int e = i >> 12, b = i & 4095;
        size_t o = (size_t)b * 2 + (e & 1) + (size_t)(e >> 1) * 2 * BB;
        out[o] += Vnet[i];
        return;
    }

    const int gi = blockIdx.x;
    const int rowBase = (gi >> 2) * 128;
    const int colBase = (gi & 3) * 128;
    const int lane = t & 63;
    const int w = t >> 6;
    const int wr = w >> 1, wc = w & 1;

    f32x4 acc[4][4] = {};
    float4 Aq[4][2];

    auto LOAD_A = [&](int kt) {
        #pragma unroll
        for (int i = 0; i < 4; i++) {
            int ch = i * 256 + t, r = ch >> 3, cb = ch & 7;
            const float* ba = qtraj + (size_t)(rowBase + r) * 512 + kt * 64 + cb * 8;
            Aq[i][0] = *(const float4*)ba;
            Aq[i][1] = *(const float4*)(ba + 4);
        }
    };
    auto WRITE_A = [&](int buf) {
        char* dA = lds + buf * 16384;
        #pragma unroll
        for (int i = 0; i < 4; i++) {
            int ch = i * 256 + t, r = ch >> 3, cb = ch & 7;
            sh8 v;
            #pragma unroll
            for (int c2 = 0; c2 < 8; c2++) {
                float qv = (c2 < 4) ? Aq[i][0][c2] : Aq[i][1][c2 - 4];
                v[c2] = (short)f2bf(qv);
            }
            *(sh8*)(dA + r * 128 + ((cb << 4) ^ ((r & 7) << 4))) = v;
        }
    };
    auto STAGE_B = [&](int kt, int buf) {
        char* dB = lds + 32768 + buf * 16384;
        #pragma unroll
        for (int i = 0; i < 4; i++) {
            unsigned ch = i * 256 + t;
            unsigned r = ch >> 3;
            unsigned scb = (ch & 7) ^ (r & 7);
            const unsigned short* src = W1qT + (size_t)(colBase + r) * 512 + (unsigned)kt * 64 + scb * 8;
            __builtin_amdgcn_global_load_lds(
                (const __attribute__((address_space(1))) unsigned int*)(const void*)src,
                (__attribute__((address_space(3))) unsigned int*)(void*)(dB + ch * 16), 16, 0, 0);
        }
    };

    LOAD_A(0);
    STAGE_B(0, 0);
    WRITE_A(0);
    asm volatile("s_waitcnt vmcnt(0) lgkmcnt(0)" ::: "memory");
    __builtin_amdgcn_s_barrier();

    for (int kt = 0; kt < 8; kt++) {
        int cur = kt & 1;
        if (kt < 7) { LOAD_A(kt + 1); STAGE_B(kt + 1, cur ^ 1); }
        char* ldsA = lds + cur * 16384;
        char* ldsB = lds + 32768 + cur * 16384;
        #pragma unroll
        for (int ks = 0; ks < 2; ks++) {
            sh8 af[4], bf_[4];
            int kb = ks * 64 + ((lane >> 4) << 4);
            #pragma unroll
            for (int mi = 0; mi < 4; mi++) {
                int m = wr * 64 + mi * 16 + (lane & 15);
                af[mi] = *(const sh8*)(ldsA + m * 128 + (kb ^ ((m & 7) << 4)));
            }
            #pragma unroll
            for (int ni = 0; ni < 4; ni++) {
                int n = wc * 64 + ni * 16 + (lane & 15);
                bf_[ni] = *(const sh8*)(ldsB + n * 128 + (kb ^ ((n & 7) << 4)));
            }
            #pragma unroll
            for (int mi = 0; mi < 4; mi++)
                #pragma unroll
                for (int ni = 0; ni < 4; ni++)
                    acc[mi][ni] = __builtin_amdgcn_mfma_f32_16x16x32_bf16(af[mi], bf_[ni], acc[mi][ni], 0, 0, 0);
        }
        if (kt < 7) WRITE_A(cur ^ 1);
        asm volatile("s_waitcnt vmcnt(0) lgkmcnt(0)" ::: "memory");
        __builtin_amdgcn_s_barrier();
    }

    float w2v[4], cv[4];
    #pragma unroll
    for (int ni = 0; ni < 4; ni++) {
        int n = colBase + wc * 64 + ni * 16 + (lane & 15);
        w2v[ni] = W2[n];
        cv[ni] = cvec[n];
    }
    #pragma unroll
    for (int mi = 0; mi < 4; mi++) {
        #pragma unroll
        for (int r = 0; r < 4; r++) {
            float partial = 0.f;
            #pragma unroll
            for (int ni = 0; ni < 4; ni++)
                partial += tanhf(acc[mi][ni][r] + cv[ni]) * w2v[ni];
            partial += __shfl_xor(partial, 1, 64);
            partial += __shfl_xor(partial, 2, 64);
            partial += __shfl_xor(partial, 4, 64);
            partial += __shfl_xor(partial, 8, 64);
            if ((lane & 15) == 0) {
                int b = rowBase + wr * 64 + mi * 16 + ((lane >> 4) << 2) + r;
                atomicAdd(out + 2 * BB + (size_t)b * 2 + 1, partial);
            }
        }
    }
}

extern "C" void kernel_launch(void* const* d_in, const int* in_sizes, int n_in,
                              void* d_out, int out_size, void* d_ws, size_t ws_size,
                              hipStream_t stream) {
    const float* u     = (const float*)d_in[0];
    const float* q0off = (const float*)d_in[1];
    const float* p0off = (const float*)d_in[2];
    const float* q0on  = (const float*)d_in[3];
    const float* p0on  = (const float*)d_in[4];
    const float* z     = (const float*)d_in[5];
    const float* W1    = (const float*)d_in[6];
    const float* b1    = (const float*)d_in[7];
    const float* W2    = (const float*)d_in[8];
    const float* b2    = (const float*)d_in[9];
    float* out = (float*)d_out;
    float* qtraj = out + 4 * BB;

    char* ws = (char*)d_ws;
    unsigned short* W1qT = (unsigned short*)ws;        // 512 KB
    float* cvec = (float*)(ws + 524288);               // 2 KB
    float* Vnet = (float*)(ws + 524288 + 2048);        // 48 KB (12288 f32)

    // offline propagator M^19 (double): q' = q + 0.1 p ; p' = 0.99 p - 0.0099 q
    double a00 = 1, a01 = 0, a10 = 0, a11 = 1;
    const double m00 = 1.0, m01 = 0.1, m10 = -0.1 * 0.1 * 0.99, m11 = 0.99;
    for (int i = 0; i < 19; i++) {
        double n00 = m00 * a00 + m01 * a10;
        double n01 = m00 * a01 + m01 * a11;
        double n10 = m10 * a00 + m11 * a10;
        double n11 = m10 * a01 + m11 * a11;
        a00 = n00; a01 = n01; a10 = n10; a11 = n11;
    }

    k_prep<<<256, 256, 0, stream>>>(W1, z, b1, W1qT, cvec, Vnet);
    k_main<<<2432, 256, 0, stream>>>(u, q0off, p0off, q0on, p0on, b2,
                                     W1qT, cvec, W2, Vnet, out, qtraj,
                                     (float)a00, (float)a01, (float)a10, (float)a11);
    k_tail<<<176, 256, 0, stream>>>(qtraj, W1qT, cvec, W2, Vnet, out);
}